// Round 22
// baseline (886.760 us; speedup 1.0000x reference)
//
#include <hip/hip_runtime.h>

// Problem constants
#define BB 4
#define SS 32
#define CC 128
#define HH 16
#define WW 32
#define HID 128
#define DEPTH 2
#define CIN 256           // CC + HID
#define COUT 512          // 4*HID
#define K9 (CIN * 9)      // 2304
#define KH 1152           // per-source K: tap-major k = tap*128 + ch
#define KFULL (2 * KH)    // 2304 = x-part rows then h-part rows
#define HW (HH * WW)      // 512
#define MM (BB * HW)      // 2048
#define ACT (BB * HW * 128) // 262144 = one activation slice (b,hw,ch)

typedef __attribute__((ext_vector_type(4))) float f32x4;
typedef __attribute__((ext_vector_type(8))) short bf16x8;

static __device__ __forceinline__ unsigned short f2bf(float f) {
    union { float f; unsigned u; } v; v.f = f;
    unsigned r = v.u + 0x7FFF + ((v.u >> 16) & 1);   // RNE
    return (unsigned short)(r >> 16);
}
static __device__ __forceinline__ float bf2f(unsigned short h) {
    union { float f; unsigned u; } v; v.u = ((unsigned)h) << 16; return v.f;
}

// ---------------------------------------------------------------------------
// Weight transpose -> single bf16 plane (RNE), k-major:
//   wh [DEPTH][COUT_g][KFULL] ushort
// k row: cin<CC -> tap*CC+cin (x block) else KH + tap*HID + (cin-CC) (h block)
// n gate-gathered: n' = (r>>4)*64 + g*16 + (r&15)
// ---------------------------------------------------------------------------
__global__ void transpose_w_kernel(const float* __restrict__ w,
                                   unsigned short* __restrict__ wh) {
    int idx = blockIdx.x * 256 + threadIdx.x;
    if (idx >= DEPTH * K9 * COUT) return;
    int n = idx % COUT;
    int k = (idx / COUT) % K9;
    int d = idx / (COUT * K9);
    int cin = k / 9, tap = k % 9;
    float v = w[(((long)(d * COUT + n) * CIN + cin) * 9) + tap];
    int row = (cin < CC) ? (tap * CC + cin) : (KH + tap * HID + (cin - CC));
    int g = n >> 7, r = n & 127;
    int ng = (r >> 4) * 64 + g * 16 + (r & 15);
    wh[((long)d * COUT + ng) * KFULL + row] = f2bf(v);
}

// ---------------------------------------------------------------------------
// Pack x [B][S][CC][HW] fp32 -> bf16 plane [s][b][hw][cc] via LDS transpose.
// grid (SS*BB, HW/64), 256 threads.
// ---------------------------------------------------------------------------
__global__ void pack_x_kernel(const float* __restrict__ x,
                              unsigned* __restrict__ xh32) {
    __shared__ unsigned lh[128 * 33];    // [cc][hw-pair], pad 33
    const int tid = threadIdx.x;
    const int sb  = blockIdx.x;          // s*BB + b
    const int s   = sb >> 2;
    const int b   = sb & 3;
    const int hw0 = blockIdx.y * 64;
    const float* src = x + ((long)(b * SS + s) * CC) * HW;

    #pragma unroll
    for (int it = 0; it < 16; ++it) {
        int cc = it * 8 + (tid >> 5);
        int hw = (tid & 31) * 2;
        float2 v = *(const float2*)&src[cc * HW + hw0 + hw];
        unsigned short h0 = f2bf(v.x), h1 = f2bf(v.y);
        lh[cc * 33 + (hw >> 1)] = (unsigned)h0 | ((unsigned)h1 << 16);
    }
    __syncthreads();
    const unsigned short* lhs = (const unsigned short*)lh;
    #pragma unroll
    for (int it = 0; it < 16; ++it) {
        int hw = it * 4 + (tid >> 6);
        int c2 = tid & 63;               // cc pair
        unsigned short a0 = lhs[(2 * c2) * 66 + hw];
        unsigned short a1 = lhs[(2 * c2 + 1) * 66 + hw];
        long o = ((long)sb * HW + hw0 + hw) * 64 + c2;
        xh32[o] = (unsigned)a0 | ((unsigned)a1 << 16);
    }
}

// ---------------------------------------------------------------------------
// Broadcast init_h/init_c[d] into bf16 h plane ([b][hw][hid]) + fp32 c
// ---------------------------------------------------------------------------
__global__ void init_state_kernel(const float* __restrict__ ih, const float* __restrict__ ic,
                                  unsigned short* __restrict__ hh,
                                  float* __restrict__ c, int d) {
    int idx = blockIdx.x * 256 + threadIdx.x;   // ACT = 262144
    int hid = idx & 127;
    hh[idx] = f2bf(ih[d * HID + hid]);
    c[idx] = ic[d * HID + hid];
}

// Zero the 256B OOB page (workspace is poisoned 0xAA before timing)
__global__ void zero_kernel(unsigned* __restrict__ zp) { zp[threadIdx.x] = 0u; }

// ---------------------------------------------------------------------------
// DUAL-LAYER fused step kernel — bf16 A/B, global_load_lds staging, BK=128,
// M=128 per wg (4 image rows), N=64; 4 waves each 64x32 (4m x 2n of 16x16
// frags): per k-sub 6 LDS reads -> 8 MFMAs (1.33x reuse; was 1:1).
// LDS traffic per unit work -25%. 96 KB LDS/wg -> 1 wg/CU; issue-ahead
// pipeline hides (L2-resident) load latency within the wg.
// Grid 256 flat, XCD-stable swizzle (2 panels/XCD). 18 phases.
// ---------------------------------------------------------------------------
__launch_bounds__(256)
__global__ void step_dual(
    const unsigned short* __restrict__ x1h, const unsigned short* __restrict__ h1h,
    float* __restrict__ c1, unsigned short* __restrict__ o1h,
    const unsigned short* __restrict__ x2h, const unsigned short* __restrict__ h2h,
    float* __restrict__ c2, unsigned short* __restrict__ o2h,
    const unsigned short* __restrict__ wh,
    const float* __restrict__ bias, const unsigned short* __restrict__ zp,
    int do1, int do2)
{
    // buf layout (ushort idx): A [0,16384) rows m*128+k (128 rows),
    // B [16384,24576) (64 rows). 2 bufs = 96 KB.
    __shared__ __align__(16) unsigned short lds[2][24576];

    const int bid  = blockIdx.x;
    const int xcd  = bid & 7;
    const int q    = bid >> 3;               // 0..31
    const int mblk = q & 15;
    const int pp   = xcd + ((q >> 4) << 3);  // panel 0..15
    const int nblk = pp & 7;
    const int z    = pp >> 3;
    if (z == 0) { if (!do1) return; } else { if (!do2) return; }

    const unsigned short* axh = z ? x2h : x1h;
    const unsigned short* ahh = z ? h2h : h1h;
    const unsigned short* wph = wh + (long)z * COUT * KFULL;
    const float* bsel  = bias + z * COUT;
    float* csel        = z ? c2 : c1;
    unsigned short* ohh = z ? o2h : o1h;

    const int m0   = mblk * 128;
    const int n0g  = nblk * 64;
    const int hid0 = nblk * 16;
    const int tid  = threadIdx.x;
    const int lane = tid & 63;
    const int wv   = tid >> 6;              // wave 0..3
    const int wm   = (wv >> 1) * 64;        // wave m offset (64x32 tile)
    const int wn   = (wv & 1) * 32;         // wave n offset
    const int b    = m0 >> 9;
    const int hwl  = m0 & 511;
    const int y0   = hwl >> 5;              // first image row (4 rows per wg)
    const long bhw = (long)b * HW;

    // A staging: 128 rows x 16 chunks = 2048 slots; wave wv rows 32wv..+31.
    // Instr s (0..7): row = wv*32 + s*4 + (lane>>4), chunk j = lane&15;
    // source chunk j^(row&7); LDS dest = wave base + s*512 + lane*8 (ushort).
    int asy_[8], asx_[8], aax_[8];
    #pragma unroll
    for (int s = 0; s < 8; ++s) {
        int row = wv * 32 + s * 4 + (lane >> 4);
        int jx  = (lane & 15) ^ (row & 7);
        asx_[s] = row & 31;
        asy_[s] = y0 + (row >> 5);
        aax_[s] = jx * 8;
    }
    // B staging: 64 rows x 16 chunks = 1024 slots; wave wv rows 16wv..+15.
    long bro_[4];
    #pragma unroll
    for (int s = 0; s < 4; ++s) {
        int row = wv * 16 + s * 4 + (lane >> 4);
        int jx  = (lane & 15) ^ (row & 7);
        bro_[s] = (long)(n0g + row) * KFULL + jx * 8;
    }

#define ISSUE(tt, pb) do {                                                        \
        const int _tt = (tt);                                                     \
        const int _tap = (_tt < 9) ? _tt : _tt - 9;                               \
        const unsigned short* _sh = (_tt < 9) ? axh : ahh;                        \
        const int _ky = _tap / 3 - 1;                                             \
        const int _kx = _tap - (_tap / 3) * 3 - 1;                                \
        const long _bk = (long)_tt * 128;                                         \
        _Pragma("unroll")                                                         \
        for (int _s = 0; _s < 8; ++_s) {                                          \
            int _yy = asy_[_s] + _ky, _xq = asx_[_s] + _kx;                       \
            bool _ok = (unsigned)_yy < (unsigned)HH && (unsigned)_xq < (unsigned)WW;\
            long _a = ((bhw + _yy * WW + _xq) << 7) + aax_[_s];                   \
            __builtin_amdgcn_global_load_lds(                                     \
                (const unsigned int*)(_ok ? _sh + _a : zp),                       \
                (unsigned int*)&lds[pb][wv * 4096 + _s * 512], 16, 0, 0);         \
        }                                                                         \
        _Pragma("unroll")                                                         \
        for (int _s = 0; _s < 4; ++_s) {                                          \
            __builtin_amdgcn_global_load_lds(                                     \
                (const unsigned int*)(wph + bro_[_s] + _bk),                      \
                (unsigned int*)&lds[pb][16384 + wv * 2048 + _s * 512], 16, 0, 0); \
        }                                                                         \
    } while (0)

    f32x4 acc[4][2];
    #pragma unroll
    for (int i = 0; i < 4; ++i)
        #pragma unroll
        for (int j = 0; j < 2; ++j)
            acc[i][j] = (f32x4){0.f,0.f,0.f,0.f};

    const int fr  = lane & 15;
    const int kqi = lane >> 4;              // 0..3 (k chunk within sub)
    int amr[4], bnr[2];
    #pragma unroll
    for (int i = 0; i < 4; ++i) amr[i] = wm + i * 16 + fr;
    #pragma unroll
    for (int j = 0; j < 2; ++j) bnr[j] = wn + j * 16 + fr;

#define COMPUTE(P) do {                                                                    \
        const unsigned short* L = &lds[P][0];                                              \
        __builtin_amdgcn_s_setprio(1);                                                     \
        _Pragma("unroll")                                                                  \
        for (int s2 = 0; s2 < 4; ++s2) {                                                   \
            const int ca = s2 * 4 + kqi;    /* chunk 0..15 */                              \
            bf16x8 fa[4], fb[2];                                                           \
            _Pragma("unroll")                                                              \
            for (int i = 0; i < 4; ++i)                                                    \
                fa[i] = *(const bf16x8*)&L[amr[i] * 128 + ((ca ^ (amr[i] & 7)) << 3)];     \
            _Pragma("unroll")                                                              \
            for (int j = 0; j < 2; ++j)                                                    \
                fb[j] = *(const bf16x8*)&L[16384 + bnr[j] * 128 + ((ca ^ (bnr[j] & 7)) << 3)];\
            _Pragma("unroll")                                                              \
            for (int i = 0; i < 4; ++i)                                                    \
                _Pragma("unroll")                                                          \
                for (int j = 0; j < 2; ++j)                                                \
                    acc[i][j] = __builtin_amdgcn_mfma_f32_16x16x32_bf16(fa[i], fb[j], acc[i][j], 0, 0, 0);\
        }                                                                                  \
        __builtin_amdgcn_s_setprio(0);                                                     \
    } while (0)

    // Pipeline: issue phase tt+1 into the other buffer, compute phase tt,
    // then barrier (compiler drains vmcnt(0) before s_barrier).
    ISSUE(0, 0);
    __syncthreads();

    int p = 0;
    for (int tt = 0; tt < 18; ++tt) {
        if (tt + 1 < 18) ISSUE(tt + 1, 1 - p);
        COMPUTE(p);
        __syncthreads();
        p ^= 1;
    }

#undef ISSUE
#undef COMPUTE

    // --- epilogue: z-tile via LDS (fits in buffer 0: 64x132 f32 = 33.8 KB),
    // then LSTM cell update (vectorized: float4 c RMW + 8B packed h). ---
    float* zt = (float*)&lds[0][0];         // [64 n_gathered][132 m]
    {
        const int rm = (lane >> 4) * 4;
        const int cn = lane & 15;
        #pragma unroll
        for (int i = 0; i < 4; ++i)
            #pragma unroll
            for (int j = 0; j < 2; ++j)
                *(float4*)&zt[(wn + j * 16 + cn) * 132 + wm + i * 16 + rm] = *(float4*)&acc[i][j];
    }
    __syncthreads();

    // 2048 cells = 128 m x 16 hid; thread: 2 x (m, 4 consecutive hid).
    #pragma unroll
    for (int i2 = 0; i2 < 2; ++i2) {
        int e  = i2 * 256 + tid;            // 0..511
        int m  = e & 127;
        int jq = e >> 7;                    // hid quad 0..3 over two iters
        // iteration i2 covers quads {0,1} then {2,3}: jq in 0..1 then 2..3
        jq = i2 * 2 + (e >> 8);             // e>>8 is 0 or 1 within iter? no:
        // recompute cleanly: e in [0,512): m = e&127, quad = e>>7 (0..3) only
        // spans 0..3 across BOTH iterations when e goes 0..511. Use that:
        jq = e >> 7;
        float g[4][4];
        #pragma unroll
        for (int ji = 0; ji < 4; ++ji) {
            int jh = jq * 4 + ji;
            #pragma unroll
            for (int gi = 0; gi < 4; ++gi)
                g[ji][gi] = zt[(gi * 16 + jh) * 132 + m] + bsel[gi * 128 + hid0 + jh];
        }
        long base = ((long)b * HW + hwl + m) * 128 + hid0 + jq * 4;
        f32x4 cv = *(const f32x4*)&csel[base];
        float hv[4];
        #pragma unroll
        for (int ji = 0; ji < 4; ++ji) {
            float si = 1.f / (1.f + expf(-g[ji][0]));
            float sf = 1.f / (1.f + expf(-g[ji][1]));
            float so = 1.f / (1.f + expf(-g[ji][3]));
            float cs = sf * cv[ji] + si * tanhf(g[ji][2]);
            cv[ji] = cs;
            hv[ji] = so * tanhf(cs);
        }
        *(f32x4*)&csel[base] = cv;
        uint2 hp;
        hp.x = (unsigned)f2bf(hv[0]) | ((unsigned)f2bf(hv[1]) << 16);
        hp.y = (unsigned)f2bf(hv[2]) | ((unsigned)f2bf(hv[3]) << 16);
        *(uint2*)&ohh[base] = hp;
    }
}

// ---------------------------------------------------------------------------
// Mean pool over HW: seq2 plane [s][b][hw][hid] -> pooled
// ---------------------------------------------------------------------------
__global__ void pool_kernel(const unsigned short* __restrict__ s2h,
                            float* __restrict__ pooled) {
    int bs = blockIdx.x;            // s*BB + b
    int j  = threadIdx.x;           // 0..127
    const unsigned short* ph = s2h + (long)bs * HW * 128 + j;
    float sum = 0.f;
    #pragma unroll 8
    for (int hw = 0; hw < HW; ++hw)
        sum += bf2f(ph[hw * 128]);
    pooled[bs * HID + j] = sum * (1.f / HW);
}

// ---------------------------------------------------------------------------
// FC + ReLU + two scalar heads.
// ---------------------------------------------------------------------------
__global__ void head_kernel(const float* __restrict__ pooled,
                            const float* __restrict__ fc_w, const float* __restrict__ fc_b,
                            const float* __restrict__ fco_w, const float* __restrict__ fco_b,
                            const float* __restrict__ fca_w, const float* __restrict__ fca_b,
                            float* __restrict__ out) {
    int bs = blockIdx.x;          // b*S + s
    int b  = bs / SS;
    int s  = bs % SS;
    int j  = threadIdx.x;
    const float* prow = pooled + (long)(s * BB + b) * HID;
    float acc = fc_b[j];
    #pragma unroll 4
    for (int k = 0; k < HID; ++k) acc += fc_w[j * HID + k] * prow[k];
    float f = fmaxf(acc, 0.f);
    __shared__ float ro[128], ra[128];
    ro[j] = f * fco_w[j];
    ra[j] = f * fca_w[j];
    __syncthreads();
    for (int off = 64; off; off >>= 1) {
        if (j < off) { ro[j] += ro[j + off]; ra[j] += ra[j + off]; }
        __syncthreads();
    }
    if (j == 0) {
        out[bs]           = ro[0] + fco_b[0];
        out[BB * SS + bs] = ra[0] + fca_b[0];
    }
}

// ---------------------------------------------------------------------------
extern "C" void kernel_launch(void* const* d_in, const int* in_sizes, int n_in,
                              void* d_out, int out_size, void* d_ws, size_t ws_size,
                              hipStream_t stream) {
    const float* x      = (const float*)d_in[0];
    const float* conv_w = (const float*)d_in[1];
    const float* conv_b = (const float*)d_in[2];
    const float* init_h = (const float*)d_in[3];
    const float* init_c = (const float*)d_in[4];
    const float* fc_w   = (const float*)d_in[5];
    const float* fc_b   = (const float*)d_in[6];
    const float* fco_w  = (const float*)d_in[7];
    const float* fco_b  = (const float*)d_in[8];
    const float* fca_w  = (const float*)d_in[9];
    const float* fca_b  = (const float*)d_in[10];
    float* out = (float*)d_out;

    // Workspace carve-up — total ~60 MB.
    unsigned short* wh  = (unsigned short*)d_ws;            // 2,359,296
    unsigned short* xph = wh  + (long)DEPTH * COUT * KFULL; // SS*ACT = 8,388,608
    unsigned short* s1h = xph + (long)SS * ACT;
    unsigned short* s2h = s1h + (long)SS * ACT;
    unsigned short* h1h = s2h + (long)SS * ACT;             // ACT each
    unsigned short* h2h = h1h + ACT;
    float* c1     = (float*)(h2h + ACT);                    // ACT f32
    float* c2     = c1 + ACT;
    float* pooled = c2 + ACT;                               // 16,384
    unsigned short* zp = (unsigned short*)(pooled + SS * BB * HID); // 256 B zeros

    transpose_w_kernel<<<(DEPTH * K9 * COUT + 255) / 256, 256, 0, stream>>>(conv_w, wh);
    pack_x_kernel<<<dim3(SS * BB, HW / 64), 256, 0, stream>>>(x, (unsigned*)xph);
    init_state_kernel<<<ACT / 256, 256, 0, stream>>>(init_h, init_c, h1h, c1, 0);
    init_state_kernel<<<ACT / 256, 256, 0, stream>>>(init_h, init_c, h2h, c2, 1);
    zero_kernel<<<1, 64, 0, stream>>>((unsigned*)zp);

    for (int t = 0; t <= SS; ++t) {
        int do1 = (t < SS) ? 1 : 0;
        int do2 = (t >= 1) ? 1 : 0;
        int t1 = (t < SS) ? t : SS - 1;          // clamped for safe ptr arith
        int u2 = (t >= 1) ? t - 1 : 0;
        const unsigned short* ax1h = xph + (long)t1 * ACT;
        const unsigned short* ah1h = (t1 == 0) ? h1h : s1h + (long)(t1 - 1) * ACT;
        unsigned short* ao1h = s1h + (long)t1 * ACT;
        const unsigned short* ax2h = s1h + (long)u2 * ACT;
        const unsigned short* ah2h = (u2 == 0) ? h2h : s2h + (long)(u2 - 1) * ACT;
        unsigned short* ao2h = s2h + (long)u2 * ACT;
        step_dual<<<256, 256, 0, stream>>>(
            ax1h, ah1h, c1, ao1h,
            ax2h, ah2h, c2, ao2h,
            wh, conv_b, zp, do1, do2);
    }

    pool_kernel<<<SS * BB, 128, 0, stream>>>(s2h, pooled);
    head_kernel<<<BB * SS, 128, 0, stream>>>(pooled, fc_w, fc_b, fco_w, fco_b, fca_w, fca_b, out);
}

// Round 23
// 696.478 us; speedup vs baseline: 1.2732x; 1.2732x over previous
//
#include <hip/hip_runtime.h>

// Problem constants
#define BB 4
#define SS 32
#define CC 128
#define HH 16
#define WW 32
#define HID 128
#define DEPTH 2
#define CIN 256           // CC + HID
#define COUT 512          // 4*HID
#define K9 (CIN * 9)      // 2304
#define KH 1152           // per-source K: tap-major k = tap*128 + ch
#define KFULL (2 * KH)    // 2304 = x-part rows then h-part rows
#define HW (HH * WW)      // 512
#define MM (BB * HW)      // 2048
#define ACT (BB * HW * 128) // 262144 = one activation slice (b,hw,ch)

typedef __attribute__((ext_vector_type(4))) float f32x4;
typedef __attribute__((ext_vector_type(8))) short bf16x8;

static __device__ __forceinline__ unsigned short f2bf(float f) {
    union { float f; unsigned u; } v; v.f = f;
    unsigned r = v.u + 0x7FFF + ((v.u >> 16) & 1);   // RNE
    return (unsigned short)(r >> 16);
}
static __device__ __forceinline__ float bf2f(unsigned short h) {
    union { float f; unsigned u; } v; v.u = ((unsigned)h) << 16; return v.f;
}

// ---------------------------------------------------------------------------
// Weight transpose -> single bf16 plane (RNE), k-major:
//   wh [DEPTH][COUT_g][KFULL] ushort
// k row: cin<CC -> tap*CC+cin (x block) else KH + tap*HID + (cin-CC) (h block)
// n gate-gathered: n' = (r>>4)*64 + g*16 + (r&15)
// ---------------------------------------------------------------------------
__global__ void transpose_w_kernel(const float* __restrict__ w,
                                   unsigned short* __restrict__ wh) {
    int idx = blockIdx.x * 256 + threadIdx.x;
    if (idx >= DEPTH * K9 * COUT) return;
    int n = idx % COUT;
    int k = (idx / COUT) % K9;
    int d = idx / (COUT * K9);
    int cin = k / 9, tap = k % 9;
    float v = w[(((long)(d * COUT + n) * CIN + cin) * 9) + tap];
    int row = (cin < CC) ? (tap * CC + cin) : (KH + tap * HID + (cin - CC));
    int g = n >> 7, r = n & 127;
    int ng = (r >> 4) * 64 + g * 16 + (r & 15);
    wh[((long)d * COUT + ng) * KFULL + row] = f2bf(v);
}

// ---------------------------------------------------------------------------
// Pack x [B][S][CC][HW] fp32 -> bf16 plane [s][b][hw][cc] via LDS transpose.
// grid (SS*BB, HW/64), 256 threads.
// ---------------------------------------------------------------------------
__global__ void pack_x_kernel(const float* __restrict__ x,
                              unsigned* __restrict__ xh32) {
    __shared__ unsigned lh[128 * 33];    // [cc][hw-pair], pad 33
    const int tid = threadIdx.x;
    const int sb  = blockIdx.x;          // s*BB + b
    const int s   = sb >> 2;
    const int b   = sb & 3;
    const int hw0 = blockIdx.y * 64;
    const float* src = x + ((long)(b * SS + s) * CC) * HW;

    #pragma unroll
    for (int it = 0; it < 16; ++it) {
        int cc = it * 8 + (tid >> 5);
        int hw = (tid & 31) * 2;
        float2 v = *(const float2*)&src[cc * HW + hw0 + hw];
        unsigned short h0 = f2bf(v.x), h1 = f2bf(v.y);
        lh[cc * 33 + (hw >> 1)] = (unsigned)h0 | ((unsigned)h1 << 16);
    }
    __syncthreads();
    const unsigned short* lhs = (const unsigned short*)lh;
    #pragma unroll
    for (int it = 0; it < 16; ++it) {
        int hw = it * 4 + (tid >> 6);
        int c2 = tid & 63;               // cc pair
        unsigned short a0 = lhs[(2 * c2) * 66 + hw];
        unsigned short a1 = lhs[(2 * c2 + 1) * 66 + hw];
        long o = ((long)sb * HW + hw0 + hw) * 64 + c2;
        xh32[o] = (unsigned)a0 | ((unsigned)a1 << 16);
    }
}

// ---------------------------------------------------------------------------
// Broadcast init_h/init_c[d] into bf16 h plane ([b][hw][hid]) + fp32 c
// ---------------------------------------------------------------------------
__global__ void init_state_kernel(const float* __restrict__ ih, const float* __restrict__ ic,
                                  unsigned short* __restrict__ hh,
                                  float* __restrict__ c, int d) {
    int idx = blockIdx.x * 256 + threadIdx.x;   // ACT = 262144
    int hid = idx & 127;
    hh[idx] = f2bf(ih[d * HID + hid]);
    c[idx] = ic[d * HID + hid];
}

// Zero the 256B OOB page (workspace is poisoned 0xAA before timing)
__global__ void zero_kernel(unsigned* __restrict__ zp) { zp[threadIdx.x] = 0u; }

// ---------------------------------------------------------------------------
// DUAL-LAYER fused step kernel — bf16 A/B, global_load_lds staging, BK=128
// (one full conv tap per phase -> 18 phases).
//  - staging = 8 async global_load_lds(16B)/thread/phase; destination is
//    wave-uniform base + lane*16; XOR swizzle on the per-lane SOURCE address.
//  - next phase's loads issued BEFORE compute; vmcnt(0) drain at the barrier
//    guarantees arrival after a full double-length compute phase.
//  - vectorized epilogue: float4 c RMW + packed 8B h store per thread.
// Per wave per phase: 16 LDS reads -> 16 MFMAs. LDS 64 KB/wg (2 x 32 KB),
// 2 wg/CU (required: cross-wg overlap hides the barrier drain).
// M=64, N=64 per wg, 256 thr = 4 waves (2m x 2n of 32x32 from 16x16 frags).
// Grid 512 flat, XCD-stable swizzle. K = 18 phases (9 x-part + 9 h-part).
// ---------------------------------------------------------------------------
__launch_bounds__(256)
__global__ void step_dual(
    const unsigned short* __restrict__ x1h, const unsigned short* __restrict__ h1h,
    float* __restrict__ c1, unsigned short* __restrict__ o1h,
    const unsigned short* __restrict__ x2h, const unsigned short* __restrict__ h2h,
    float* __restrict__ c2, unsigned short* __restrict__ o2h,
    const unsigned short* __restrict__ wh,
    const float* __restrict__ bias, const unsigned short* __restrict__ zp,
    int do1, int do2)
{
    // buf layout (ushort idx): A [0,8192) rows m*128+k, B [8192,16384).
    // 2 bufs = 64 KB.
    __shared__ __align__(16) unsigned short lds[2][16384];

    const int bid  = blockIdx.x;
    const int xcd  = bid & 7;
    const int q    = bid >> 3;               // 0..63
    const int mblk = q & 31;
    const int pp   = xcd + ((q >> 5) << 3);  // panel 0..15
    const int nblk = pp & 7;
    const int z    = pp >> 3;
    if (z == 0) { if (!do1) return; } else { if (!do2) return; }

    const unsigned short* axh = z ? x2h : x1h;
    const unsigned short* ahh = z ? h2h : h1h;
    const unsigned short* wph = wh + (long)z * COUT * KFULL;
    const float* bsel  = bias + z * COUT;
    float* csel        = z ? c2 : c1;
    unsigned short* ohh = z ? o2h : o1h;

    const int m0   = mblk * 64;
    const int n0g  = nblk * 64;
    const int hid0 = nblk * 16;
    const int tid  = threadIdx.x;
    const int lane = tid & 63;
    const int wv   = tid >> 6;              // wave 0..3
    const int wm   = (wv >> 1) * 32;        // wave m offset (32x32 tile)
    const int wn   = (wv & 1) * 32;         // wave n offset
    const int b    = m0 >> 9;
    const int hwl  = m0 & 511;
    const int y0   = hwl >> 5;              // first image row (2 rows per wg)
    const long bhw = (long)b * HW;

    // Staging geometry (per plane): wave wv stages rows 16wv..16wv+15, each
    // row = 128 k (16 chunks of 8 ushorts). Instruction s (0..3): lane slot
    // row = wv*16 + s*4 + (lane>>4), chunk j = lane&15; source chunk
    // j^(row&7) (XOR swizzle); LDS dest = wave-uniform base + lane*16.
    int sy_[4], sx_[4], ax_[4];
    long bro_[4];
    #pragma unroll
    for (int s = 0; s < 4; ++s) {
        int row = wv * 16 + s * 4 + (lane >> 4);
        int jx  = (lane & 15) ^ (row & 7);
        sx_[s] = row & 31;
        sy_[s] = y0 + (row >> 5);
        ax_[s] = jx * 8;
        bro_[s] = (long)(n0g + row) * KFULL + jx * 8;
    }

#define ISSUE(tt, pb) do {                                                        \
        const int _tt = (tt);                                                     \
        const int _tap = (_tt < 9) ? _tt : _tt - 9;                               \
        const unsigned short* _sh = (_tt < 9) ? axh : ahh;                        \
        const int _ky = _tap / 3 - 1;                                             \
        const int _kx = _tap - (_tap / 3) * 3 - 1;                                \
        const long _bk = (long)_tt * 128;                                         \
        _Pragma("unroll")                                                         \
        for (int _s = 0; _s < 4; ++_s) {                                          \
            int _yy = sy_[_s] + _ky, _xq = sx_[_s] + _kx;                         \
            bool _ok = (unsigned)_yy < (unsigned)HH && (unsigned)_xq < (unsigned)WW;\
            long _a = ((bhw + _yy * WW + _xq) << 7) + ax_[_s];                    \
            __builtin_amdgcn_global_load_lds(                                     \
                (const unsigned int*)(_ok ? _sh + _a : zp),                       \
                (unsigned int*)&lds[pb][wv * 2048 + _s * 512], 16, 0, 0);         \
            __builtin_amdgcn_global_load_lds(                                     \
                (const unsigned int*)(wph + bro_[_s] + _bk),                      \
                (unsigned int*)&lds[pb][8192 + wv * 2048 + _s * 512], 16, 0, 0);  \
        }                                                                         \
    } while (0)

    f32x4 acc00 = (f32x4){0.f,0.f,0.f,0.f};
    f32x4 acc01 = (f32x4){0.f,0.f,0.f,0.f};
    f32x4 acc10 = (f32x4){0.f,0.f,0.f,0.f};
    f32x4 acc11 = (f32x4){0.f,0.f,0.f,0.f};

    const int fr  = lane & 15;
    const int kqi = lane >> 4;              // 0..3 (k chunk within sub)
    const int am0 = wm + fr;                // A rows (2 m-frags)
    const int am1 = wm + 16 + fr;
    const int bn0 = wn + fr;                // B rows (2 n-frags)
    const int bn1 = wn + 16 + fr;

#define COMPUTE(P) do {                                                                   \
        const unsigned short* L = &lds[P][0];                                             \
        __builtin_amdgcn_s_setprio(1);                                                    \
        _Pragma("unroll")                                                                 \
        for (int s2 = 0; s2 < 4; ++s2) {                                                  \
            const int ca = s2 * 4 + kqi;    /* chunk 0..15 */                             \
            bf16x8 fa0 = *(const bf16x8*)&L[am0 * 128 + ((ca ^ (am0 & 7)) << 3)];         \
            bf16x8 fa1 = *(const bf16x8*)&L[am1 * 128 + ((ca ^ (am1 & 7)) << 3)];         \
            bf16x8 fb0 = *(const bf16x8*)&L[8192 + bn0 * 128 + ((ca ^ (bn0 & 7)) << 3)];  \
            bf16x8 fb1 = *(const bf16x8*)&L[8192 + bn1 * 128 + ((ca ^ (bn1 & 7)) << 3)];  \
            acc00 = __builtin_amdgcn_mfma_f32_16x16x32_bf16(fa0, fb0, acc00, 0, 0, 0);    \
            acc01 = __builtin_amdgcn_mfma_f32_16x16x32_bf16(fa0, fb1, acc01, 0, 0, 0);    \
            acc10 = __builtin_amdgcn_mfma_f32_16x16x32_bf16(fa1, fb0, acc10, 0, 0, 0);    \
            acc11 = __builtin_amdgcn_mfma_f32_16x16x32_bf16(fa1, fb1, acc11, 0, 0, 0);    \
        }                                                                                 \
        __builtin_amdgcn_s_setprio(0);                                                    \
    } while (0)

    // Pipeline: issue phase tt+1 into the other buffer, compute phase tt,
    // then barrier (compiler drains vmcnt(0) before s_barrier).
    ISSUE(0, 0);
    __syncthreads();

    int p = 0;
    for (int tt = 0; tt < 18; ++tt) {
        if (tt + 1 < 18) ISSUE(tt + 1, 1 - p);
        COMPUTE(p);
        __syncthreads();
        p ^= 1;
    }

#undef ISSUE
#undef COMPUTE

    // --- epilogue: z-tile via LDS (fits in buffer 0), LSTM cell update ---
    float* zt = (float*)&lds[0][0];         // [64 n_gathered][68 m] = 17.4 KB
    {
        const int rm = (lane >> 4) * 4;
        const int cn = lane & 15;
        *(float4*)&zt[(wn + cn) * 68 + wm + rm]           = *(float4*)&acc00;
        *(float4*)&zt[(wn + 16 + cn) * 68 + wm + rm]      = *(float4*)&acc01;
        *(float4*)&zt[(wn + cn) * 68 + wm + 16 + rm]      = *(float4*)&acc10;
        *(float4*)&zt[(wn + 16 + cn) * 68 + wm + 16 + rm] = *(float4*)&acc11;
    }
    __syncthreads();

    // Each thread: one m, 4 consecutive hid -> float4 c RMW + 8B packed h.
    {
        const int m    = tid & 63;
        const int jset = tid >> 6;          // 0..3
        float g[4][4];
        #pragma unroll
        for (int ji = 0; ji < 4; ++ji) {
            int jh = jset * 4 + ji;
            #pragma unroll
            for (int gi = 0; gi < 4; ++gi)
                g[ji][gi] = zt[(gi * 16 + jh) * 68 + m] + bsel[gi * 128 + hid0 + jh];
        }
        long base = ((long)b * HW + hwl + m) * 128 + hid0 + jset * 4;
        f32x4 cv = *(const f32x4*)&csel[base];
        float hv[4];
        #pragma unroll
        for (int ji = 0; ji < 4; ++ji) {
            float si = 1.f / (1.f + expf(-g[ji][0]));
            float sf = 1.f / (1.f + expf(-g[ji][1]));
            float so = 1.f / (1.f + expf(-g[ji][3]));
            float cs = sf * cv[ji] + si * tanhf(g[ji][2]);
            cv[ji] = cs;
            hv[ji] = so * tanhf(cs);
        }
        *(f32x4*)&csel[base] = cv;
        uint2 hp;
        hp.x = (unsigned)f2bf(hv[0]) | ((unsigned)f2bf(hv[1]) << 16);
        hp.y = (unsigned)f2bf(hv[2]) | ((unsigned)f2bf(hv[3]) << 16);
        *(uint2*)&ohh[base] = hp;
    }
}

// ---------------------------------------------------------------------------
// Mean pool over HW: seq2 plane [s][b][hw][hid] -> pooled
// ---------------------------------------------------------------------------
__global__ void pool_kernel(const unsigned short* __restrict__ s2h,
                            float* __restrict__ pooled) {
    int bs = blockIdx.x;            // s*BB + b
    int j  = threadIdx.x;           // 0..127
    const unsigned short* ph = s2h + (long)bs * HW * 128 + j;
    float sum = 0.f;
    #pragma unroll 8
    for (int hw = 0; hw < HW; ++hw)
        sum += bf2f(ph[hw * 128]);
    pooled[bs * HID + j] = sum * (1.f / HW);
}

// ---------------------------------------------------------------------------
// FC + ReLU + two scalar heads.
// ---------------------------------------------------------------------------
__global__ void head_kernel(const float* __restrict__ pooled,
                            const float* __restrict__ fc_w, const float* __restrict__ fc_b,
                            const float* __restrict__ fco_w, const float* __restrict__ fco_b,
                            const float* __restrict__ fca_w, const float* __restrict__ fca_b,
                            float* __restrict__ out) {
    int bs = blockIdx.x;          // b*S + s
    int b  = bs / SS;
    int s  = bs % SS;
    int j  = threadIdx.x;
    const float* prow = pooled + (long)(s * BB + b) * HID;
    float acc = fc_b[j];
    #pragma unroll 4
    for (int k = 0; k < HID; ++k) acc += fc_w[j * HID + k] * prow[k];
    float f = fmaxf(acc, 0.f);
    __shared__ float ro[128], ra[128];
    ro[j] = f * fco_w[j];
    ra[j] = f * fca_w[j];
    __syncthreads();
    for (int off = 64; off; off >>= 1) {
        if (j < off) { ro[j] += ro[j + off]; ra[j] += ra[j + off]; }
        __syncthreads();
    }
    if (j == 0) {
        out[bs]           = ro[0] + fco_b[0];
        out[BB * SS + bs] = ra[0] + fca_b[0];
    }
}

// ---------------------------------------------------------------------------
extern "C" void kernel_launch(void* const* d_in, const int* in_sizes, int n_in,
                              void* d_out, int out_size, void* d_ws, size_t ws_size,
                              hipStream_t stream) {
    const float* x      = (const float*)d_in[0];
    const float* conv_w = (const float*)d_in[1];
    const float* conv_b = (const float*)d_in[2];
    const float* init_h = (const float*)d_in[3];
    const float* init_c = (const float*)d_in[4];
    const float* fc_w   = (const float*)d_in[5];
    const float* fc_b   = (const float*)d_in[6];
    const float* fco_w  = (const float*)d_in[7];
    const float* fco_b  = (const float*)d_in[8];
    const float* fca_w  = (const float*)d_in[9];
    const float* fca_b  = (const float*)d_in[10];
    float* out = (float*)d_out;

    // Workspace carve-up — total ~60 MB.
    unsigned short* wh  = (unsigned short*)d_ws;            // 2,359,296
    unsigned short* xph = wh  + (long)DEPTH * COUT * KFULL; // SS*ACT = 8,388,608
    unsigned short* s1h = xph + (long)SS * ACT;
    unsigned short* s2h = s1h + (long)SS * ACT;
    unsigned short* h1h = s2h + (long)SS * ACT;             // ACT each
    unsigned short* h2h = h1h + ACT;
    float* c1     = (float*)(h2h + ACT);                    // ACT f32
    float* c2     = c1 + ACT;
    float* pooled = c2 + ACT;                               // 16,384
    unsigned short* zp = (unsigned short*)(pooled + SS * BB * HID); // 256 B zeros

    transpose_w_kernel<<<(DEPTH * K9 * COUT + 255) / 256, 256, 0, stream>>>(conv_w, wh);
    pack_x_kernel<<<dim3(SS * BB, HW / 64), 256, 0, stream>>>(x, (unsigned*)xph);
    init_state_kernel<<<ACT / 256, 256, 0, stream>>>(init_h, init_c, h1h, c1, 0);
    init_state_kernel<<<ACT / 256, 256, 0, stream>>>(init_h, init_c, h2h, c2, 1);
    zero_kernel<<<1, 64, 0, stream>>>((unsigned*)zp);

    for (int t = 0; t <= SS; ++t) {
        int do1 = (t < SS) ? 1 : 0;
        int do2 = (t >= 1) ? 1 : 0;
        int t1 = (t < SS) ? t : SS - 1;          // clamped for safe ptr arith
        int u2 = (t >= 1) ? t - 1 : 0;
        const unsigned short* ax1h = xph + (long)t1 * ACT;
        const unsigned short* ah1h = (t1 == 0) ? h1h : s1h + (long)(t1 - 1) * ACT;
        unsigned short* ao1h = s1h + (long)t1 * ACT;
        const unsigned short* ax2h = s1h + (long)u2 * ACT;
        const unsigned short* ah2h = (u2 == 0) ? h2h : s2h + (long)(u2 - 1) * ACT;
        unsigned short* ao2h = s2h + (long)u2 * ACT;
        step_dual<<<512, 256, 0, stream>>>(
            ax1h, ah1h, c1, ao1h,
            ax2h, ah2h, c2, ao2h,
            wh, conv_b, zp, do1, do2);
    }

    pool_kernel<<<SS * BB, 128, 0, stream>>>(s2h, pooled);
    head_kernel<<<BB * SS, 128, 0, stream>>>(pooled, fc_w, fc_b, fco_w, fco_b, fca_w, fca_b, out);
}